// Round 1
// baseline (3844.424 us; speedup 1.0000x reference)
//
#include <hip/hip_runtime.h>
#include <math.h>

#define B_ 32
#define L_ 512
#define H_ 336
#define C_ 321
#define K_ 8
#define S_ 8
#define FREQ_ 169   // H/2+1
#define G_ 17       // 2K+1
#define LH_ 848     // L+H
#define F_FEAT 520  // L+K
#define EPS_ 1e-5f

#ifndef M_PIf
#define M_PIf 3.14159265358979323846f
#endif

// ---------------- K0: twiddle tables ----------------
// ctab[f*H + h] = cos(2*pi*f*h/H), stab likewise sin. Angle reduced mod H in ints.
__global__ __launch_bounds__(256) void k_tables(float* __restrict__ ctab, float* __restrict__ stab) {
    int idx = blockIdx.x * 256 + threadIdx.x;
    if (idx >= FREQ_ * H_) return;
    int f = idx / H_, h = idx % H_;
    int m = (f * h) % H_;
    float th = (float)m * (2.0f * M_PIf / (float)H_);
    float s, c;
    sincosf(th, &s, &c);
    ctab[idx] = c;
    stab[idx] = s;
}

// ---------------- K1: LayerNorm ----------------
__global__ __launch_bounds__(256) void k_ln(const float* __restrict__ x,
                                            float* __restrict__ full,
                                            float* __restrict__ muv,
                                            float* __restrict__ nrm) {
    int bc = blockIdx.x;                 // b*C + c
    int b = bc / C_, c = bc % C_;
    int tid = threadIdx.x;
    const float* xb = x + (size_t)b * L_ * C_ + c;
    float v0 = xb[(size_t)tid * C_];
    float v1 = xb[(size_t)(tid + 256) * C_];
    float s = v0 + v1, q = v0 * v0 + v1 * v1;
    #pragma unroll
    for (int off = 32; off > 0; off >>= 1) {
        s += __shfl_down(s, off);
        q += __shfl_down(q, off);
    }
    __shared__ float ss[4], qq[4];
    __shared__ float smu, snrm;
    int wid = tid >> 6, lane = tid & 63;
    if (lane == 0) { ss[wid] = s; qq[wid] = q; }
    __syncthreads();
    if (tid == 0) {
        float S = ss[0] + ss[1] + ss[2] + ss[3];
        float Q = qq[0] + qq[1] + qq[2] + qq[3];
        float mu = S / (float)L_;
        float var = Q / (float)L_ - mu * mu;
        float n = sqrtf(var + EPS_);
        smu = mu; snrm = n;
        muv[bc] = mu; nrm[bc] = n;
    }
    __syncthreads();
    float mu = smu, n = snrm, inv = 1.0f / n;
    float* dst = full + (size_t)bc * LH_;
    dst[tid]       = (v0 - mu) * inv;
    dst[tid + 256] = (v1 - mu) * inv;
}

// ---------------- K2: y_hat GEMM: full[:,512:848] = xn @ Wb^T + bb ----------------
__global__ __launch_bounds__(256) void k_gemm_yhat(const float* __restrict__ full_r,
                                                   const float* __restrict__ Wb,
                                                   const float* __restrict__ bb,
                                                   float* __restrict__ full_w) {
    __shared__ float As[16][65];
    __shared__ float Bs[16][65];
    const int M = B_ * C_;
    int tid = threadIdx.x;
    int row0 = blockIdx.y * 64, col0 = blockIdx.x * 64;
    int lm = tid >> 2;             // 0..63
    int lk = (tid & 3) << 2;       // 0,4,8,12
    int tx = tid & 15, ty = tid >> 4;
    float acc[4][4] = {{0.f}};
    for (int k0 = 0; k0 < L_; k0 += 16) {
        int gm = row0 + lm;
        float4 av = make_float4(0.f, 0.f, 0.f, 0.f);
        if (gm < M) av = *reinterpret_cast<const float4*>(full_r + (size_t)gm * LH_ + k0 + lk);
        As[lk + 0][lm] = av.x; As[lk + 1][lm] = av.y; As[lk + 2][lm] = av.z; As[lk + 3][lm] = av.w;
        int gn = col0 + lm;
        float4 bv = make_float4(0.f, 0.f, 0.f, 0.f);
        if (gn < H_) bv = *reinterpret_cast<const float4*>(Wb + (size_t)gn * L_ + k0 + lk);
        Bs[lk + 0][lm] = bv.x; Bs[lk + 1][lm] = bv.y; Bs[lk + 2][lm] = bv.z; Bs[lk + 3][lm] = bv.w;
        __syncthreads();
        #pragma unroll
        for (int kk = 0; kk < 16; ++kk) {
            float a_[4], b_[4];
            #pragma unroll
            for (int i = 0; i < 4; ++i) a_[i] = As[kk][ty * 4 + i];
            #pragma unroll
            for (int j = 0; j < 4; ++j) b_[j] = Bs[kk][tx * 4 + j];
            #pragma unroll
            for (int i = 0; i < 4; ++i)
                #pragma unroll
                for (int j = 0; j < 4; ++j)
                    acc[i][j] += a_[i] * b_[j];
        }
        __syncthreads();
    }
    #pragma unroll
    for (int i = 0; i < 4; ++i) {
        int gm = row0 + ty * 4 + i;
        if (gm >= M) continue;
        #pragma unroll
        for (int j = 0; j < 4; ++j) {
            int gn = col0 + tx * 4 + j;
            if (gn < H_) full_w[(size_t)gm * LH_ + L_ + gn] = acc[i][j] + bb[gn];
        }
    }
}

// ---------------- K3: r_soft + feat @ Wc^T + softmax -> p ----------------
__global__ __launch_bounds__(64) void k_p(const float* __restrict__ full,
                                          const float* __restrict__ r,
                                          const float* __restrict__ Wc,
                                          const float* __restrict__ bcv,
                                          float* __restrict__ p_out) {
    int bc = blockIdx.x;
    int tid = threadIdx.x;
    __shared__ float rsoft[8];
    if (tid == 0) {
        const float* rr = r + (size_t)bc * K_;
        float a[8]; float m = 1.0f;
        #pragma unroll
        for (int k = 0; k < 8; ++k) { a[k] = fabsf(rr[k]); m = fmaxf(m, a[k]); }
        float Z = expf(1.0f - m);
        float e[8];
        #pragma unroll
        for (int k = 0; k < 8; ++k) { e[k] = expf(a[k] - m); Z += e[k]; }
        float inv = 1.0f / Z;
        #pragma unroll
        for (int k = 0; k < 8; ++k) rsoft[k] = e[k] * inv;
    }
    __syncthreads();
    const float* xrow = full + (size_t)bc * LH_;
    float acc[8] = {0.f, 0.f, 0.f, 0.f, 0.f, 0.f, 0.f, 0.f};
    for (int f = tid; f < F_FEAT; f += 64) {
        float xf = (f < L_) ? xrow[f] : rsoft[f - L_];
        #pragma unroll
        for (int s = 0; s < 8; ++s) acc[s] += xf * Wc[s * F_FEAT + f];
    }
    #pragma unroll
    for (int s = 0; s < 8; ++s) {
        #pragma unroll
        for (int off = 32; off > 0; off >>= 1) acc[s] += __shfl_down(acc[s], off);
    }
    if (tid == 0) {
        float m = -1e30f;
        #pragma unroll
        for (int s = 0; s < 8; ++s) { acc[s] += bcv[s]; m = fmaxf(m, acc[s]); }
        float Z = 0.f; float e[8];
        #pragma unroll
        for (int s = 0; s < 8; ++s) { e[s] = expf(acc[s] - m); Z += e[s]; }
        float inv = 1.0f / Z;
        #pragma unroll
        for (int s = 0; s < 8; ++s) p_out[(size_t)bc * 8 + s] = e[s] * inv;
    }
}

// ---------------- K4: fused per-(b,c) main kernel ----------------
__global__ __launch_bounds__(256) void k_main(const float* __restrict__ full,
                                              const float* __restrict__ p,
                                              const int* __restrict__ leader,
                                              const int* __restrict__ shiftp,
                                              const float* __restrict__ st_re,
                                              const float* __restrict__ st_im,
                                              const float* __restrict__ Wm_re,
                                              const float* __restrict__ Wm_im,
                                              const float* __restrict__ bm_re,
                                              const float* __restrict__ bm_im,
                                              const float* __restrict__ muv,
                                              const float* __restrict__ nrm,
                                              const float* __restrict__ ctab,
                                              const float* __restrict__ stab,
                                              float* __restrict__ out) {
    int bc = blockIdx.x;
    int b = bc / C_, c = bc % C_;
    int tid = threadIdx.x;

    __shared__ float sig[9][H_];                 // 8 gathered windows + y_hat
    __shared__ float Fre[G_ * FREQ_], Fim[G_ * FREQ_];
    __shared__ float zre[3 * FREQ_], zim[3 * FREQ_];
    __shared__ float mre[FREQ_], mim[FREQ_];
    __shared__ float ps[8];

    if (tid < 8) ps[tid] = p[(size_t)bc * 8 + tid];

    // gather signals: ss_k[h] = full[b, lead_k, L - shift_k + h]; sig[8] = y_hat
    #pragma unroll
    for (int k = 0; k < 8; ++k) {
        int lead = leader[(size_t)bc * K_ + k];
        int sh = shiftp[(size_t)bc * K_ + k];
        const float* src = full + ((size_t)b * C_ + lead) * LH_ + (L_ - sh);
        for (int h = tid; h < H_; h += 256) sig[k][h] = src[h];
    }
    {
        const float* src = full + (size_t)bc * LH_ + L_;
        for (int h = tid; h < H_; h += 256) sig[8][h] = src[h];
    }
    __syncthreads();

    // filters F[g][f] = sum_s p_s * states[s][g][f]
    for (int idx = tid; idx < G_ * FREQ_; idx += 256) {
        float fr = 0.f, fi = 0.f;
        #pragma unroll
        for (int s = 0; s < 8; ++s) {
            float wv = ps[s];
            fr += wv * st_re[s * (G_ * FREQ_) + idx];
            fi += wv * st_im[s * (G_ * FREQ_) + idx];
        }
        Fre[idx] = fr; Fim[idx] = fi;
    }
    __syncthreads();

    // DFT per frequency + per-f combine -> z
    if (tid < FREQ_) {
        int f = tid;
        float Xr[9], Xi[9];
        #pragma unroll
        for (int k = 0; k < 9; ++k) { Xr[k] = 0.f; Xi[k] = 0.f; }
        const float* cr = ctab + (size_t)f * H_;
        const float* sr = stab + (size_t)f * H_;
        for (int h = 0; h < H_; h += 4) {
            float4 cc = *reinterpret_cast<const float4*>(cr + h);
            float4 sv = *reinterpret_cast<const float4*>(sr + h);
            #pragma unroll
            for (int k = 0; k < 9; ++k) {
                float4 v = *reinterpret_cast<const float4*>(&sig[k][h]);
                Xr[k] += v.x * cc.x + v.y * cc.y + v.z * cc.z + v.w * cc.w;
                Xi[k] -= v.x * sv.x + v.y * sv.y + v.z * sv.z + v.w * sv.w;
            }
        }
        float Yr = Xr[8], Yi = Xi[8];
        float z1r = 0.f, z1i = 0.f, z2r = 0.f, z2i = 0.f;
        #pragma unroll
        for (int k = 0; k < 8; ++k) {
            float f1r = Fre[k * FREQ_ + f], f1i = Fim[k * FREQ_ + f];
            float ar = Xr[k] * f1r - Xi[k] * f1i;
            float ai = Xr[k] * f1i + Xi[k] * f1r;
            z1r += ar; z1i += ai;
            float f2r = Fre[(8 + k) * FREQ_ + f], f2i = Fim[(8 + k) * FREQ_ + f];
            float dr = ar - Yr, di = ai - Yi;
            z2r += dr * f2r - di * f2i;
            z2i += dr * f2i + di * f2r;
        }
        float f3r = Fre[16 * FREQ_ + f], f3i = Fim[16 * FREQ_ + f];
        zre[f] = z1r;              zim[f] = z1i;
        zre[FREQ_ + f] = z2r;      zim[FREQ_ + f] = z2i;
        zre[2 * FREQ_ + f] = Yr * f3r - Yi * f3i;
        zim[2 * FREQ_ + f] = Yr * f3i + Yi * f3r;
    }
    __syncthreads();

    // mixing: mixed[g] = sum_j z[j] * Wm[g, j] + bm[g]
    if (tid < FREQ_) {
        int g = tid;
        const float* wr = Wm_re + (size_t)g * (3 * FREQ_);
        const float* wi = Wm_im + (size_t)g * (3 * FREQ_);
        float mr = bm_re[g], mi = bm_im[g];
        for (int j = 0; j < 3 * FREQ_; ++j) {
            float zr = zre[j], zi = zim[j];
            float wre = wr[j], wim = wi[j];
            mr += zr * wre - zi * wim;
            mi += zr * wim + zi * wre;
        }
        mre[g] = mr; mim[g] = mi;
    }
    __syncthreads();

    // irfft (numpy semantics: only Re of DC & Nyquist) + denorm + transpose store
    float mu = muv[bc], n = nrm[bc];
    for (int h = tid; h < H_; h += 256) {
        float acc = mre[0];
        acc += (h & 1) ? -mre[FREQ_ - 1] : mre[FREQ_ - 1];
        float s2 = 0.f;
        for (int f = 1; f < FREQ_ - 1; ++f) {
            s2 += mre[f] * ctab[(size_t)f * H_ + h] - mim[f] * stab[(size_t)f * H_ + h];
        }
        acc += 2.0f * s2;
        float yadd = acc * (1.0f / (float)H_);
        float y = (sig[8][h] + yadd) * n + mu;
        out[(size_t)b * (H_ * C_) + (size_t)h * C_ + c] = y;
    }
}

extern "C" void kernel_launch(void* const* d_in, const int* in_sizes, int n_in,
                              void* d_out, int out_size, void* d_ws, size_t ws_size,
                              hipStream_t stream) {
    const float* x     = (const float*)d_in[0];
    const float* r     = (const float*)d_in[1];
    const float* Wb    = (const float*)d_in[2];
    const float* bb    = (const float*)d_in[3];
    const float* Wc    = (const float*)d_in[4];
    const float* bcv   = (const float*)d_in[5];
    const float* st_re = (const float*)d_in[6];
    const float* st_im = (const float*)d_in[7];
    const float* Wm_re = (const float*)d_in[8];
    const float* Wm_im = (const float*)d_in[9];
    const float* bm_re = (const float*)d_in[10];
    const float* bm_im = (const float*)d_in[11];
    const int* leader  = (const int*)d_in[12];
    const int* shiftp  = (const int*)d_in[13];
    float* out = (float*)d_out;

    char* w = (char*)d_ws;
    auto carve = [&](size_t bytes) {
        char* ptr = w;
        w += (bytes + 255) & ~(size_t)255;
        return (float*)ptr;
    };
    float* ctab = carve((size_t)FREQ_ * H_ * 4);
    float* stab = carve((size_t)FREQ_ * H_ * 4);
    float* full = carve((size_t)B_ * C_ * LH_ * 4);
    float* muv  = carve((size_t)B_ * C_ * 4);
    float* nrm  = carve((size_t)B_ * C_ * 4);
    float* pbuf = carve((size_t)B_ * C_ * 8 * 4);

    hipLaunchKernelGGL(k_tables, dim3((FREQ_ * H_ + 255) / 256), dim3(256), 0, stream, ctab, stab);
    hipLaunchKernelGGL(k_ln, dim3(B_ * C_), dim3(256), 0, stream, x, full, muv, nrm);
    hipLaunchKernelGGL(k_gemm_yhat, dim3((H_ + 63) / 64, (B_ * C_ + 63) / 64), dim3(256), 0, stream,
                       full, Wb, bb, full);
    hipLaunchKernelGGL(k_p, dim3(B_ * C_), dim3(64), 0, stream, full, r, Wc, bcv, pbuf);
    hipLaunchKernelGGL(k_main, dim3(B_ * C_), dim3(256), 0, stream, full, pbuf, leader, shiftp,
                       st_re, st_im, Wm_re, Wm_im, bm_re, bm_im, muv, nrm, ctab, stab, out);
}

// Round 2
// 1400.143 us; speedup vs baseline: 2.7457x; 2.7457x over previous
//
#include <hip/hip_runtime.h>
#include <math.h>

#define B_ 32
#define L_ 512
#define H_ 336
#define C_ 321
#define K_ 8
#define S_ 8
#define FREQ_ 169   // H/2+1
#define G_ 17       // 2K+1
#define LH_ 848     // L+H
#define F_FEAT 520  // L+K
#define EPS_ 1e-5f

#ifndef M_PIf
#define M_PIf 3.14159265358979323846f
#endif

// ---------------- K0: twiddle tables (both layouts) ----------------
// ctab[f*H + h] (f-major, for irfft: lanes=h coalesced)
// ctabT[h*FREQ + f] (h-major, for DFT: lanes=f coalesced)
__global__ __launch_bounds__(256) void k_tables(float* __restrict__ ctab, float* __restrict__ stab,
                                                float* __restrict__ ctabT, float* __restrict__ stabT) {
    int idx = blockIdx.x * 256 + threadIdx.x;
    if (idx >= FREQ_ * H_) return;
    int f = idx / H_, h = idx % H_;
    int m = (f * h) % H_;
    float th = (float)m * (2.0f * M_PIf / (float)H_);
    float s, c;
    sincosf(th, &s, &c);
    ctab[idx] = c;
    stab[idx] = s;
    ctabT[h * FREQ_ + f] = c;
    stabT[h * FREQ_ + f] = s;
}

// ---------------- K0b: prep — transpose Wm, interleave states ----------------
__global__ __launch_bounds__(256) void k_prep(const float* __restrict__ Wm_re,
                                              const float* __restrict__ Wm_im,
                                              const float* __restrict__ st_re,
                                              const float* __restrict__ st_im,
                                              float2* __restrict__ WmT2,
                                              float2* __restrict__ stc2) {
    int idx = blockIdx.x * 256 + threadIdx.x;
    const int NW = 3 * FREQ_ * FREQ_;   // 507*169
    if (idx < NW) {
        int j = idx / FREQ_, g = idx % FREQ_;
        WmT2[idx] = make_float2(Wm_re[(size_t)g * (3 * FREQ_) + j],
                                Wm_im[(size_t)g * (3 * FREQ_) + j]);
    }
    if (idx < S_ * G_ * FREQ_) {
        stc2[idx] = make_float2(st_re[idx], st_im[idx]);
    }
}

// ---------------- K1: LayerNorm ----------------
__global__ __launch_bounds__(256) void k_ln(const float* __restrict__ x,
                                            float* __restrict__ full,
                                            float* __restrict__ muv,
                                            float* __restrict__ nrm) {
    int bc = blockIdx.x;                 // b*C + c
    int b = bc / C_, c = bc % C_;
    int tid = threadIdx.x;
    const float* xb = x + (size_t)b * L_ * C_ + c;
    float v0 = xb[(size_t)tid * C_];
    float v1 = xb[(size_t)(tid + 256) * C_];
    float s = v0 + v1, q = v0 * v0 + v1 * v1;
    #pragma unroll
    for (int off = 32; off > 0; off >>= 1) {
        s += __shfl_down(s, off);
        q += __shfl_down(q, off);
    }
    __shared__ float ss[4], qq[4];
    __shared__ float smu, snrm;
    int wid = tid >> 6, lane = tid & 63;
    if (lane == 0) { ss[wid] = s; qq[wid] = q; }
    __syncthreads();
    if (tid == 0) {
        float S = ss[0] + ss[1] + ss[2] + ss[3];
        float Q = qq[0] + qq[1] + qq[2] + qq[3];
        float mu = S / (float)L_;
        float var = Q / (float)L_ - mu * mu;
        float n = sqrtf(var + EPS_);
        smu = mu; snrm = n;
        muv[bc] = mu; nrm[bc] = n;
    }
    __syncthreads();
    float mu = smu, n = snrm, inv = 1.0f / n;
    float* dst = full + (size_t)bc * LH_;
    dst[tid]       = (v0 - mu) * inv;
    dst[tid + 256] = (v1 - mu) * inv;
}

// ---------------- K2: y_hat GEMM: full[:,512:848] = xn @ Wb^T + bb ----------------
__global__ __launch_bounds__(256) void k_gemm_yhat(const float* __restrict__ full_r,
                                                   const float* __restrict__ Wb,
                                                   const float* __restrict__ bb,
                                                   float* __restrict__ full_w) {
    __shared__ float As[16][65];
    __shared__ float Bs[16][65];
    const int M = B_ * C_;
    int tid = threadIdx.x;
    int row0 = blockIdx.y * 64, col0 = blockIdx.x * 64;
    int lm = tid >> 2;
    int lk = (tid & 3) << 2;
    int tx = tid & 15, ty = tid >> 4;
    float acc[4][4] = {{0.f}};
    for (int k0 = 0; k0 < L_; k0 += 16) {
        int gm = row0 + lm;
        float4 av = make_float4(0.f, 0.f, 0.f, 0.f);
        if (gm < M) av = *reinterpret_cast<const float4*>(full_r + (size_t)gm * LH_ + k0 + lk);
        As[lk + 0][lm] = av.x; As[lk + 1][lm] = av.y; As[lk + 2][lm] = av.z; As[lk + 3][lm] = av.w;
        int gn = col0 + lm;
        float4 bv = make_float4(0.f, 0.f, 0.f, 0.f);
        if (gn < H_) bv = *reinterpret_cast<const float4*>(Wb + (size_t)gn * L_ + k0 + lk);
        Bs[lk + 0][lm] = bv.x; Bs[lk + 1][lm] = bv.y; Bs[lk + 2][lm] = bv.z; Bs[lk + 3][lm] = bv.w;
        __syncthreads();
        #pragma unroll
        for (int kk = 0; kk < 16; ++kk) {
            float a_[4], b_[4];
            #pragma unroll
            for (int i = 0; i < 4; ++i) a_[i] = As[kk][ty * 4 + i];
            #pragma unroll
            for (int j = 0; j < 4; ++j) b_[j] = Bs[kk][tx * 4 + j];
            #pragma unroll
            for (int i = 0; i < 4; ++i)
                #pragma unroll
                for (int j = 0; j < 4; ++j)
                    acc[i][j] += a_[i] * b_[j];
        }
        __syncthreads();
    }
    #pragma unroll
    for (int i = 0; i < 4; ++i) {
        int gm = row0 + ty * 4 + i;
        if (gm >= M) continue;
        #pragma unroll
        for (int j = 0; j < 4; ++j) {
            int gn = col0 + tx * 4 + j;
            if (gn < H_) full_w[(size_t)gm * LH_ + L_ + gn] = acc[i][j] + bb[gn];
        }
    }
}

// ---------------- K3: r_soft + feat @ Wc^T + softmax -> p ----------------
__global__ __launch_bounds__(64) void k_p(const float* __restrict__ full,
                                          const float* __restrict__ r,
                                          const float* __restrict__ Wc,
                                          const float* __restrict__ bcv,
                                          float* __restrict__ p_out) {
    int bc = blockIdx.x;
    int tid = threadIdx.x;
    __shared__ float rsoft[8];
    if (tid == 0) {
        const float* rr = r + (size_t)bc * K_;
        float a[8]; float m = 1.0f;
        #pragma unroll
        for (int k = 0; k < 8; ++k) { a[k] = fabsf(rr[k]); m = fmaxf(m, a[k]); }
        float Z = expf(1.0f - m);
        float e[8];
        #pragma unroll
        for (int k = 0; k < 8; ++k) { e[k] = expf(a[k] - m); Z += e[k]; }
        float inv = 1.0f / Z;
        #pragma unroll
        for (int k = 0; k < 8; ++k) rsoft[k] = e[k] * inv;
    }
    __syncthreads();
    const float* xrow = full + (size_t)bc * LH_;
    float acc[8] = {0.f, 0.f, 0.f, 0.f, 0.f, 0.f, 0.f, 0.f};
    for (int f = tid; f < F_FEAT; f += 64) {
        float xf = (f < L_) ? xrow[f] : rsoft[f - L_];
        #pragma unroll
        for (int s = 0; s < 8; ++s) acc[s] += xf * Wc[s * F_FEAT + f];
    }
    #pragma unroll
    for (int s = 0; s < 8; ++s) {
        #pragma unroll
        for (int off = 32; off > 0; off >>= 1) acc[s] += __shfl_down(acc[s], off);
    }
    if (tid == 0) {
        float m = -1e30f;
        #pragma unroll
        for (int s = 0; s < 8; ++s) { acc[s] += bcv[s]; m = fmaxf(m, acc[s]); }
        float Z = 0.f; float e[8];
        #pragma unroll
        for (int s = 0; s < 8; ++s) { e[s] = expf(acc[s] - m); Z += e[s]; }
        float inv = 1.0f / Z;
        #pragma unroll
        for (int s = 0; s < 8; ++s) p_out[(size_t)bc * 8 + s] = e[s] * inv;
    }
}

// ---------------- K4: fused per-(b,c) main kernel (coalesced, slim LDS) ----------------
__global__ __launch_bounds__(256) void k_main(const float* __restrict__ full,
                                              const float* __restrict__ p,
                                              const int* __restrict__ leader,
                                              const int* __restrict__ shiftp,
                                              const float2* __restrict__ stc2,
                                              const float2* __restrict__ WmT2,
                                              const float* __restrict__ bm_re,
                                              const float* __restrict__ bm_im,
                                              const float* __restrict__ muv,
                                              const float* __restrict__ nrm,
                                              const float* __restrict__ ctab,
                                              const float* __restrict__ stab,
                                              const float* __restrict__ ctabT,
                                              const float* __restrict__ stabT,
                                              float* __restrict__ ytmp) {
    int bc = blockIdx.x;
    int b = bc / C_, c = bc % C_;
    (void)c;
    int tid = threadIdx.x;

    __shared__ float sig[9][H_];        // 8 gathered windows + y_hat (12.1 KB)
    __shared__ float2 zc[3 * FREQ_];    // z (4.1 KB)
    __shared__ float2 mc[FREQ_];        // mixed (1.4 KB)
    __shared__ float ps[8];

    if (tid < 8) ps[tid] = p[(size_t)bc * 8 + tid];

    // gather: sig[k][h] = full[b, lead_k, L - shift_k + h]; sig[8] = y_hat
    #pragma unroll
    for (int k = 0; k < 8; ++k) {
        int lead = leader[(size_t)bc * K_ + k];
        int sh = shiftp[(size_t)bc * K_ + k];
        const float* src = full + ((size_t)b * C_ + lead) * LH_ + (L_ - sh);
        for (int h = tid; h < H_; h += 256) sig[k][h] = src[h];
    }
    {
        const float* src = full + (size_t)bc * LH_ + L_;
        for (int h = tid; h < H_; h += 256) sig[8][h] = src[h];
    }
    __syncthreads();

    // ---- DFT per frequency (coalesced transposed tables) + filter-combine -> z ----
    if (tid < FREQ_) {
        int f = tid;
        float Xr[9], Xi[9];
        #pragma unroll
        for (int k = 0; k < 9; ++k) { Xr[k] = 0.f; Xi[k] = 0.f; }
        const float* ct = ctabT + f;
        const float* st = stabT + f;
        for (int h = 0; h < H_; h += 2) {
            float c0 = ct[(size_t)h * FREQ_];
            float s0 = st[(size_t)h * FREQ_];
            float c1 = ct[(size_t)(h + 1) * FREQ_];
            float s1 = st[(size_t)(h + 1) * FREQ_];
            #pragma unroll
            for (int k = 0; k < 9; ++k) {
                float2 v = *reinterpret_cast<const float2*>(&sig[k][h]);
                Xr[k] += v.x * c0 + v.y * c1;
                Xi[k] -= v.x * s0 + v.y * s1;
            }
        }
        float pr[8];
        #pragma unroll
        for (int s = 0; s < 8; ++s) pr[s] = ps[s];

        float Yr = Xr[8], Yi = Xi[8];
        float z1r = 0.f, z1i = 0.f, z2r = 0.f, z2i = 0.f;
        #pragma unroll
        for (int k = 0; k < 8; ++k) {
            float f1r = 0.f, f1i = 0.f, f2r = 0.f, f2i = 0.f;
            #pragma unroll
            for (int s = 0; s < 8; ++s) {
                float2 v1 = stc2[(size_t)s * (G_ * FREQ_) + k * FREQ_ + f];
                float2 v2 = stc2[(size_t)s * (G_ * FREQ_) + (8 + k) * FREQ_ + f];
                f1r += pr[s] * v1.x; f1i += pr[s] * v1.y;
                f2r += pr[s] * v2.x; f2i += pr[s] * v2.y;
            }
            float ar = Xr[k] * f1r - Xi[k] * f1i;
            float ai = Xr[k] * f1i + Xi[k] * f1r;
            z1r += ar; z1i += ai;
            float dr = ar - Yr, di = ai - Yi;
            z2r += dr * f2r - di * f2i;
            z2i += dr * f2i + di * f2r;
        }
        float f3r = 0.f, f3i = 0.f;
        #pragma unroll
        for (int s = 0; s < 8; ++s) {
            float2 v3 = stc2[(size_t)s * (G_ * FREQ_) + 16 * FREQ_ + f];
            f3r += pr[s] * v3.x; f3i += pr[s] * v3.y;
        }
        zc[f]             = make_float2(z1r, z1i);
        zc[FREQ_ + f]     = make_float2(z2r, z2i);
        zc[2 * FREQ_ + f] = make_float2(Yr * f3r - Yi * f3i, Yr * f3i + Yi * f3r);
    }
    __syncthreads();

    // ---- mixing: mixed[g] = sum_j z[j] * Wm[g, j] + bm[g] (coalesced WmT2) ----
    if (tid < FREQ_) {
        int g = tid;
        float mr = bm_re[g], mi = bm_im[g];
        const float2* wp = WmT2 + g;
        #pragma unroll 3
        for (int j = 0; j < 3 * FREQ_; ++j) {
            float2 w = wp[(size_t)j * FREQ_];
            float2 z = zc[j];
            mr += z.x * w.x - z.y * w.y;
            mi += z.x * w.y + z.y * w.x;
        }
        mc[g] = make_float2(mr, mi);
    }
    __syncthreads();

    // ---- irfft + denorm, coalesced store to ytmp[bc][h] ----
    float mu = muv[bc], n = nrm[bc];
    for (int h = tid; h < H_; h += 256) {
        float acc = mc[0].x;
        acc += (h & 1) ? -mc[FREQ_ - 1].x : mc[FREQ_ - 1].x;
        float s2 = 0.f;
        for (int f = 1; f < FREQ_ - 1; ++f) {
            float2 m = mc[f];
            s2 += m.x * ctab[(size_t)f * H_ + h] - m.y * stab[(size_t)f * H_ + h];
        }
        acc += 2.0f * s2;
        float yadd = acc * (1.0f / (float)H_);
        float y = (sig[8][h] + yadd) * n + mu;
        ytmp[(size_t)bc * H_ + h] = y;
    }
}

// ---------------- K5: transpose ytmp[b][c][h] -> out[b][h][c] ----------------
__global__ __launch_bounds__(256) void k_out_t(const float* __restrict__ ytmp,
                                               float* __restrict__ out) {
    __shared__ float tile[32][33];
    int b = blockIdx.z;
    int h0 = blockIdx.x * 32, c0 = blockIdx.y * 32;
    int tx = threadIdx.x & 31, ty = threadIdx.x >> 5;   // 32 x 8
    #pragma unroll
    for (int i = 0; i < 4; ++i) {
        int cc = c0 + ty + i * 8, hh = h0 + tx;
        if (cc < C_ && hh < H_)
            tile[ty + i * 8][tx] = ytmp[((size_t)b * C_ + cc) * H_ + hh];
    }
    __syncthreads();
    #pragma unroll
    for (int i = 0; i < 4; ++i) {
        int hh = h0 + ty + i * 8, cc = c0 + tx;
        if (cc < C_ && hh < H_)
            out[((size_t)b * H_ + hh) * C_ + cc] = tile[tx][ty + i * 8];
    }
}

extern "C" void kernel_launch(void* const* d_in, const int* in_sizes, int n_in,
                              void* d_out, int out_size, void* d_ws, size_t ws_size,
                              hipStream_t stream) {
    const float* x     = (const float*)d_in[0];
    const float* r     = (const float*)d_in[1];
    const float* Wb    = (const float*)d_in[2];
    const float* bb    = (const float*)d_in[3];
    const float* Wc    = (const float*)d_in[4];
    const float* bcv   = (const float*)d_in[5];
    const float* st_re = (const float*)d_in[6];
    const float* st_im = (const float*)d_in[7];
    const float* Wm_re = (const float*)d_in[8];
    const float* Wm_im = (const float*)d_in[9];
    const float* bm_re = (const float*)d_in[10];
    const float* bm_im = (const float*)d_in[11];
    const int* leader  = (const int*)d_in[12];
    const int* shiftp  = (const int*)d_in[13];
    float* out = (float*)d_out;

    char* w = (char*)d_ws;
    auto carve = [&](size_t bytes) {
        char* ptr = w;
        w += (bytes + 255) & ~(size_t)255;
        return (void*)ptr;
    };
    float*  ctab  = (float*) carve((size_t)FREQ_ * H_ * 4);
    float*  stab  = (float*) carve((size_t)FREQ_ * H_ * 4);
    float*  ctabT = (float*) carve((size_t)FREQ_ * H_ * 4);
    float*  stabT = (float*) carve((size_t)FREQ_ * H_ * 4);
    float*  full  = (float*) carve((size_t)B_ * C_ * LH_ * 4);
    float*  muv   = (float*) carve((size_t)B_ * C_ * 4);
    float*  nrm   = (float*) carve((size_t)B_ * C_ * 4);
    float*  pbuf  = (float*) carve((size_t)B_ * C_ * 8 * 4);
    float2* WmT2  = (float2*)carve((size_t)3 * FREQ_ * FREQ_ * 8);
    float2* stc2  = (float2*)carve((size_t)S_ * G_ * FREQ_ * 8);
    float*  ytmp  = (float*) carve((size_t)B_ * C_ * H_ * 4);

    hipLaunchKernelGGL(k_tables, dim3((FREQ_ * H_ + 255) / 256), dim3(256), 0, stream,
                       ctab, stab, ctabT, stabT);
    hipLaunchKernelGGL(k_prep, dim3((3 * FREQ_ * FREQ_ + 255) / 256), dim3(256), 0, stream,
                       Wm_re, Wm_im, st_re, st_im, WmT2, stc2);
    hipLaunchKernelGGL(k_ln, dim3(B_ * C_), dim3(256), 0, stream, x, full, muv, nrm);
    hipLaunchKernelGGL(k_gemm_yhat, dim3((H_ + 63) / 64, (B_ * C_ + 63) / 64), dim3(256), 0, stream,
                       full, Wb, bb, full);
    hipLaunchKernelGGL(k_p, dim3(B_ * C_), dim3(64), 0, stream, full, r, Wc, bcv, pbuf);
    hipLaunchKernelGGL(k_main, dim3(B_ * C_), dim3(256), 0, stream, full, pbuf, leader, shiftp,
                       stc2, WmT2, bm_re, bm_im, muv, nrm, ctab, stab, ctabT, stabT, ytmp);
    hipLaunchKernelGGL(k_out_t, dim3((H_ + 31) / 32, (C_ + 31) / 32, B_), dim3(256), 0, stream,
                       ytmp, out);
}

// Round 3
// 545.972 us; speedup vs baseline: 7.0414x; 2.5645x over previous
//
#include <hip/hip_runtime.h>
#include <math.h>

#define B_ 32
#define L_ 512
#define H_ 336
#define C_ 321
#define K_ 8
#define S_ 8
#define FREQ_ 169   // H/2+1
#define G_ 17       // 2K+1
#define LH_ 848     // L+H
#define F_FEAT 520  // L+K
#define EPS_ 1e-5f
#define BCN_ (B_ * C_)   // 10272

#ifndef M_PIf
#define M_PIf 3.14159265358979323846f
#endif

typedef __attribute__((ext_vector_type(8))) short short8v;
typedef __attribute__((ext_vector_type(4))) float f32x4;

__device__ __forceinline__ unsigned short f2bf(float x) {
    unsigned u = __builtin_bit_cast(unsigned, x);
    u += 0x7FFFu + ((u >> 16) & 1u);
    return (unsigned short)(u >> 16);
}
__device__ __forceinline__ float bf2f(unsigned short h) {
    return __builtin_bit_cast(float, (unsigned)h << 16);
}

// ================= prep kernels: build MFMA-fragment-swizzled B matrices ==========
// Fragment layout (16x16x32 bf16): b-frag lane l holds B[kc*32 + (l>>4)*8 + i][nt*16 + (l&15)].
// Stored flat: elem((kc*NT + nt)*512 + l*8 + i).

// DFT table: K=352 (336 used), N=352 (338 used). col 2f=cos(2pi k f/H), 2f+1=-sin.
__global__ void k_prep_dft(unsigned short* __restrict__ T) {   // grid 11*22, 64 thr
    int blk = blockIdx.x, kc = blk / 22, nt = blk % 22, lane = threadIdx.x;
    int n = nt * 16 + (lane & 15);
    int kb = kc * 32 + (lane >> 4) * 8;
    int f = n >> 1;
    unsigned short* dst = T + (size_t)blk * 512 + lane * 8;
    for (int i = 0; i < 8; ++i) {
        int k = kb + i;
        float val = 0.f;
        if (k < H_ && n < 2 * FREQ_) {
            int m = (k * f) % H_;
            float s, c;
            sincosf((float)m * (2.0f * M_PIf / (float)H_), &s, &c);
            val = (n & 1) ? -s : c;
        }
        dst[i] = f2bf(val);
    }
}

// irfft table: K=352 (338 used; row 2f = cos, 2f+1 = -sin), N=336.
__global__ void k_prep_ir(unsigned short* __restrict__ T) {    // grid 11*21, 64 thr
    int blk = blockIdx.x, kc = blk / 21, nt = blk % 21, lane = threadIdx.x;
    int h = nt * 16 + (lane & 15);
    int kb = kc * 32 + (lane >> 4) * 8;
    unsigned short* dst = T + (size_t)blk * 512 + lane * 8;
    for (int i = 0; i < 8; ++i) {
        int k = kb + i;
        float val = 0.f;
        if (k < 2 * FREQ_) {
            int f = k >> 1;
            int m = (f * h) % H_;
            float s, c;
            sincosf((float)m * (2.0f * M_PIf / (float)H_), &s, &c);
            val = (k & 1) ? -s : c;
        }
        dst[i] = f2bf(val);
    }
}

// Mixing matrix: K=1024 (rows 0..506 = zr part, 512..1018 = zi part), N=352 (338 used).
// col 2g: re(mixed) needs  wr (from zr) and -wi (from zi)
// col 2g+1: im(mixed) needs wi (from zr) and  wr (from zi)
__global__ void k_prep_w2(const float* __restrict__ Wm_re, const float* __restrict__ Wm_im,
                          unsigned short* __restrict__ T) {    // grid 32*22, 64 thr
    int blk = blockIdx.x, kc = blk / 22, nt = blk % 22, lane = threadIdx.x;
    int n = nt * 16 + (lane & 15);
    int kb = kc * 32 + (lane >> 4) * 8;
    int g = n >> 1;
    unsigned short* dst = T + (size_t)blk * 512 + lane * 8;
    for (int i = 0; i < 8; ++i) {
        int k = kb + i;
        float val = 0.f;
        if (n < 2 * FREQ_) {
            if (k < 3 * FREQ_) {
                int j = k;
                val = (n & 1) ? Wm_im[(size_t)g * (3 * FREQ_) + j]
                              : Wm_re[(size_t)g * (3 * FREQ_) + j];
            } else if (k >= 512 && k < 512 + 3 * FREQ_) {
                int j = k - 512;
                val = (n & 1) ? Wm_re[(size_t)g * (3 * FREQ_) + j]
                              : -Wm_im[(size_t)g * (3 * FREQ_) + j];
            }
        }
        dst[i] = f2bf(val);
    }
}

// Wb for y_hat GEMM: B[k][n] = Wb[n][k]. K=512, N=336.
__global__ void k_prep_wb(const float* __restrict__ Wb, unsigned short* __restrict__ T) { // grid 16*21, 64 thr
    int blk = blockIdx.x, kc = blk / 21, nt = blk % 21, lane = threadIdx.x;
    int n = nt * 16 + (lane & 15);
    int kb = kc * 32 + (lane >> 4) * 8;
    unsigned short* dst = T + (size_t)blk * 512 + lane * 8;
    for (int i = 0; i < 8; ++i) {
        int k = kb + i;
        dst[i] = f2bf(Wb[(size_t)n * L_ + k]);
    }
}

// states interleave (for k_z)
__global__ __launch_bounds__(256) void k_prep_st(const float* __restrict__ st_re,
                                                 const float* __restrict__ st_im,
                                                 float2* __restrict__ stc2) {
    int idx = blockIdx.x * 256 + threadIdx.x;
    if (idx < S_ * G_ * FREQ_) stc2[idx] = make_float2(st_re[idx], st_im[idx]);
}

// ================= K1: LayerNorm (writes f32 full + bf16 xn) =================
__global__ __launch_bounds__(256) void k_ln(const float* __restrict__ x,
                                            float* __restrict__ full,
                                            unsigned short* __restrict__ xnbf,
                                            float* __restrict__ muv,
                                            float* __restrict__ nrm) {
    int bc = blockIdx.x;
    int b = bc / C_, c = bc % C_;
    int tid = threadIdx.x;
    const float* xb = x + (size_t)b * L_ * C_ + c;
    float v0 = xb[(size_t)tid * C_];
    float v1 = xb[(size_t)(tid + 256) * C_];
    float s = v0 + v1, q = v0 * v0 + v1 * v1;
    #pragma unroll
    for (int off = 32; off > 0; off >>= 1) {
        s += __shfl_down(s, off);
        q += __shfl_down(q, off);
    }
    __shared__ float ss[4], qq[4];
    __shared__ float smu, snrm;
    int wid = tid >> 6, lane = tid & 63;
    if (lane == 0) { ss[wid] = s; qq[wid] = q; }
    __syncthreads();
    if (tid == 0) {
        float S = ss[0] + ss[1] + ss[2] + ss[3];
        float Q = qq[0] + qq[1] + qq[2] + qq[3];
        float mu = S / (float)L_;
        float var = Q / (float)L_ - mu * mu;
        float n = sqrtf(var + EPS_);
        smu = mu; snrm = n;
        muv[bc] = mu; nrm[bc] = n;
    }
    __syncthreads();
    float mu = smu, inv = 1.0f / snrm;
    float a0 = (v0 - mu) * inv, a1 = (v1 - mu) * inv;
    float* dst = full + (size_t)bc * LH_;
    dst[tid] = a0; dst[tid + 256] = a1;
    xnbf[(size_t)bc * L_ + tid] = f2bf(a0);
    xnbf[(size_t)bc * L_ + tid + 256] = f2bf(a1);
}

// ================= K2: y_hat via MFMA: full[:,512:848] = xn @ Wb^T + bb ======
__global__ __launch_bounds__(256) void k_yhat(const unsigned short* __restrict__ xnbf,
                                              const unsigned short* __restrict__ Wbsw,
                                              const float* __restrict__ bb,
                                              float* __restrict__ full) {
    int bc0 = blockIdx.x * 32;
    int tid = threadIdx.x, w = tid >> 6, lane = tid & 63;
    const int NTB[5] = {0, 6, 11, 16, 21};
    int nt0 = NTB[w], ntn = NTB[w + 1] - nt0;
    int r15 = lane & 15, kg = lane >> 4;
    f32x4 acc[2][6];
    #pragma unroll
    for (int mf = 0; mf < 2; ++mf)
        #pragma unroll
        for (int j = 0; j < 6; ++j) acc[mf][j] = (f32x4){0.f, 0.f, 0.f, 0.f};
    for (int kc = 0; kc < 16; ++kc) {
        short8v a[2];
        #pragma unroll
        for (int mf = 0; mf < 2; ++mf)
            a[mf] = *(const short8v*)(xnbf + ((size_t)(bc0 + mf * 16 + r15) * L_ + kc * 32 + kg * 8));
        #pragma unroll
        for (int j = 0; j < 6; ++j) {
            if (j >= ntn) continue;
            short8v bfr = *(const short8v*)(Wbsw + ((size_t)(kc * 21 + nt0 + j) * 512 + lane * 8));
            #pragma unroll
            for (int mf = 0; mf < 2; ++mf)
                acc[mf][j] = __builtin_amdgcn_mfma_f32_16x16x32_bf16(a[mf], bfr, acc[mf][j], 0, 0, 0);
        }
    }
    #pragma unroll
    for (int mf = 0; mf < 2; ++mf)
        #pragma unroll
        for (int j = 0; j < 6; ++j) {
            if (j >= ntn) continue;
            int n_ = (nt0 + j) * 16 + r15;
            #pragma unroll
            for (int reg = 0; reg < 4; ++reg) {
                int bc = bc0 + mf * 16 + kg * 4 + reg;
                full[(size_t)bc * LH_ + L_ + n_] = acc[mf][j][reg] + bb[n_];
            }
        }
}

// ================= K3: r_soft + feat @ Wc^T + softmax -> p ===================
__global__ __launch_bounds__(64) void k_p(const float* __restrict__ full,
                                          const float* __restrict__ r,
                                          const float* __restrict__ Wc,
                                          const float* __restrict__ bcv,
                                          float* __restrict__ p_out) {
    int bc = blockIdx.x;
    int tid = threadIdx.x;
    __shared__ float rsoft[8];
    if (tid == 0) {
        const float* rr = r + (size_t)bc * K_;
        float a[8]; float m = 1.0f;
        #pragma unroll
        for (int k = 0; k < 8; ++k) { a[k] = fabsf(rr[k]); m = fmaxf(m, a[k]); }
        float Z = expf(1.0f - m);
        float e[8];
        #pragma unroll
        for (int k = 0; k < 8; ++k) { e[k] = expf(a[k] - m); Z += e[k]; }
        float inv = 1.0f / Z;
        #pragma unroll
        for (int k = 0; k < 8; ++k) rsoft[k] = e[k] * inv;
    }
    __syncthreads();
    const float* xrow = full + (size_t)bc * LH_;
    float acc[8] = {0.f, 0.f, 0.f, 0.f, 0.f, 0.f, 0.f, 0.f};
    for (int f = tid; f < F_FEAT; f += 64) {
        float xf = (f < L_) ? xrow[f] : rsoft[f - L_];
        #pragma unroll
        for (int s = 0; s < 8; ++s) acc[s] += xf * Wc[s * F_FEAT + f];
    }
    #pragma unroll
    for (int s = 0; s < 8; ++s) {
        #pragma unroll
        for (int off = 32; off > 0; off >>= 1) acc[s] += __shfl_down(acc[s], off);
    }
    if (tid == 0) {
        float m = -1e30f;
        #pragma unroll
        for (int s = 0; s < 8; ++s) { acc[s] += bcv[s]; m = fmaxf(m, acc[s]); }
        float Z = 0.f; float e[8];
        #pragma unroll
        for (int s = 0; s < 8; ++s) { e[s] = expf(acc[s] - m); Z += e[s]; }
        float inv = 1.0f / Z;
        #pragma unroll
        for (int s = 0; s < 8; ++s) p_out[(size_t)bc * 8 + s] = e[s] * inv;
    }
}

// ================= K4: DFT via MFMA =========================================
// Block: 4 bc (64 A-rows). A in LDS (bf16, rows 0..8 real, 9..15 zero).
// Waves partition 22 n-tiles; each wave: 4 M-frags x <=6 N-frags.
// X output: bf16 [bc][9][352], col 2f = Re, 2f+1 = Im.
__global__ __launch_bounds__(256) void k_dft(const float* __restrict__ full,
                                             const int* __restrict__ leader,
                                             const int* __restrict__ shiftp,
                                             const unsigned short* __restrict__ Tsw,
                                             unsigned short* __restrict__ Xbf) {
    __shared__ unsigned short A[64 * 360];
    int tid = threadIdx.x, w = tid >> 6, lane = tid & 63;
    int bc0 = blockIdx.x * 4;

    unsigned* A32 = (unsigned*)A;
    for (int i = tid; i < 64 * 360 / 2; i += 256) A32[i] = 0;
    __syncthreads();

    int bc = bc0 + w;
    int b = bc / C_;
    for (int k = 0; k < 9; ++k) {
        const float* src;
        if (k < 8) {
            int lead = leader[(size_t)bc * K_ + k];
            int sh = shiftp[(size_t)bc * K_ + k];
            src = full + ((size_t)b * C_ + lead) * LH_ + (L_ - sh);
        } else {
            src = full + (size_t)bc * LH_ + L_;
        }
        unsigned* dst = (unsigned*)(A + (size_t)(w * 16 + k) * 360);
        for (int j = lane; j < 168; j += 64) {
            float2 v = *(const float2*)(src + 2 * j);
            dst[j] = (unsigned)f2bf(v.x) | ((unsigned)f2bf(v.y) << 16);
        }
    }
    __syncthreads();

    const int NTB[5] = {0, 6, 12, 17, 22};
    int nt0 = NTB[w], ntn = NTB[w + 1] - nt0;
    int r15 = lane & 15, kg = lane >> 4;
    f32x4 acc[4][6];
    #pragma unroll
    for (int mf = 0; mf < 4; ++mf)
        #pragma unroll
        for (int j = 0; j < 6; ++j) acc[mf][j] = (f32x4){0.f, 0.f, 0.f, 0.f};

    for (int kc = 0; kc < 11; ++kc) {
        short8v a[4];
        #pragma unroll
        for (int mf = 0; mf < 4; ++mf)
            a[mf] = *(const short8v*)(A + (size_t)(mf * 16 + r15) * 360 + kc * 32 + kg * 8);
        #pragma unroll
        for (int j = 0; j < 6; ++j) {
            if (j >= ntn) continue;
            short8v bfr = *(const short8v*)(Tsw + ((size_t)(kc * 22 + nt0 + j) * 512 + lane * 8));
            #pragma unroll
            for (int mf = 0; mf < 4; ++mf)
                acc[mf][j] = __builtin_amdgcn_mfma_f32_16x16x32_bf16(a[mf], bfr, acc[mf][j], 0, 0, 0);
        }
    }

    #pragma unroll
    for (int mf = 0; mf < 4; ++mf)
        #pragma unroll
        for (int j = 0; j < 6; ++j) {
            if (j >= ntn) continue;
            int col = (nt0 + j) * 16 + r15;
            #pragma unroll
            for (int reg = 0; reg < 4; ++reg) {
                int sig = kg * 4 + reg;
                if (sig < 9)
                    Xbf[((size_t)(bc0 + mf) * 9 + sig) * 352 + col] = f2bf(acc[mf][j][reg]);
            }
        }
}

// ================= K5: filter build + combine -> z (bf16) ====================
// z layout per bc (1024): [0..168]=z1r, [169..337]=z2r, [338..506]=z3r, [507..511]=0,
//                         [512..680]=z1i, [681..849]=z2i, [850..1018]=z3i, [1019..1023]=0
__global__ __launch_bounds__(256) void k_z(const unsigned short* __restrict__ Xbf,
                                           const float* __restrict__ pbuf,
                                           const float2* __restrict__ stc2,
                                           unsigned short* __restrict__ zbf) {
    int tid = threadIdx.x, w = tid >> 6, lane = tid & 63;
    int bc = blockIdx.x * 4 + w;
    float ps[8];
    #pragma unroll
    for (int s = 0; s < 8; ++s) ps[s] = pbuf[(size_t)bc * 8 + s];
    unsigned short* zrow = zbf + (size_t)bc * 1024;
    if (lane < 5) { zrow[507 + lane] = 0; zrow[1019 + lane] = 0; }

    const unsigned* Xr = (const unsigned*)(Xbf + (size_t)bc * 9 * 352);
    for (int f = lane; f < FREQ_; f += 64) {
        float Xre[9], Xim[9];
        #pragma unroll
        for (int k = 0; k < 9; ++k) {
            unsigned v = Xr[k * 176 + f];
            Xre[k] = bf2f((unsigned short)(v & 0xffff));
            Xim[k] = bf2f((unsigned short)(v >> 16));
        }
        float Yr = Xre[8], Yi = Xim[8];
        float z1r = 0.f, z1i = 0.f, z2r = 0.f, z2i = 0.f;
        #pragma unroll
        for (int k = 0; k < 8; ++k) {
            float f1r = 0.f, f1i = 0.f, f2r = 0.f, f2i = 0.f;
            #pragma unroll
            for (int s = 0; s < 8; ++s) {
                float2 v1 = stc2[(size_t)s * (G_ * FREQ_) + k * FREQ_ + f];
                float2 v2 = stc2[(size_t)s * (G_ * FREQ_) + (8 + k) * FREQ_ + f];
                f1r += ps[s] * v1.x; f1i += ps[s] * v1.y;
                f2r += ps[s] * v2.x; f2i += ps[s] * v2.y;
            }
            float ar = Xre[k] * f1r - Xim[k] * f1i;
            float ai = Xre[k] * f1i + Xim[k] * f1r;
            z1r += ar; z1i += ai;
            float dr = ar - Yr, di = ai - Yi;
            z2r += dr * f2r - di * f2i;
            z2i += dr * f2i + di * f2r;
        }
        float f3r = 0.f, f3i = 0.f;
        #pragma unroll
        for (int s = 0; s < 8; ++s) {
            float2 v3 = stc2[(size_t)s * (G_ * FREQ_) + 16 * FREQ_ + f];
            f3r += ps[s] * v3.x; f3i += ps[s] * v3.y;
        }
        zrow[f]       = f2bf(z1r);  zrow[512 + f]       = f2bf(z1i);
        zrow[169 + f] = f2bf(z2r);  zrow[512 + 169 + f] = f2bf(z2i);
        zrow[338 + f] = f2bf(Yr * f3r - Yi * f3i);
        zrow[512 + 338 + f] = f2bf(Yr * f3i + Yi * f3r);
    }
}

// ================= K6: mixing via MFMA ======================================
// Mx[bc][352] bf16: col 2g = (re+bm_re)*w/H, 2g+1 = (im+bm_im)*w/H, cols>=338 zero.
__global__ __launch_bounds__(256) void k_mix(const unsigned short* __restrict__ zbf,
                                             const unsigned short* __restrict__ W2sw,
                                             const float* __restrict__ bm_re,
                                             const float* __restrict__ bm_im,
                                             unsigned short* __restrict__ Mx) {
    int bc0 = blockIdx.x * 32;
    int tid = threadIdx.x, w = tid >> 6, lane = tid & 63;
    const int NTB[5] = {0, 6, 12, 17, 22};
    int nt0 = NTB[w], ntn = NTB[w + 1] - nt0;
    int r15 = lane & 15, kg = lane >> 4;
    f32x4 acc[2][6];
    #pragma unroll
    for (int mf = 0; mf < 2; ++mf)
        #pragma unroll
        for (int j = 0; j < 6; ++j) acc[mf][j] = (f32x4){0.f, 0.f, 0.f, 0.f};
    for (int kc = 0; kc < 32; ++kc) {
        short8v a[2];
        #pragma unroll
        for (int mf = 0; mf < 2; ++mf)
            a[mf] = *(const short8v*)(zbf + ((size_t)(bc0 + mf * 16 + r15) * 1024 + kc * 32 + kg * 8));
        #pragma unroll
        for (int j = 0; j < 6; ++j) {
            if (j >= ntn) continue;
            short8v bfr = *(const short8v*)(W2sw + ((size_t)(kc * 22 + nt0 + j) * 512 + lane * 8));
            #pragma unroll
            for (int mf = 0; mf < 2; ++mf)
                acc[mf][j] = __builtin_amdgcn_mfma_f32_16x16x32_bf16(a[mf], bfr, acc[mf][j], 0, 0, 0);
        }
    }
    #pragma unroll
    for (int mf = 0; mf < 2; ++mf)
        #pragma unroll
        for (int j = 0; j < 6; ++j) {
            if (j >= ntn) continue;
            int col = (nt0 + j) * 16 + r15;
            #pragma unroll
            for (int reg = 0; reg < 4; ++reg) {
                int bc = bc0 + mf * 16 + kg * 4 + reg;
                float v = 0.f;
                if (col < 2 * FREQ_) {
                    int g = col >> 1;
                    float bias = (col & 1) ? bm_im[g] : bm_re[g];
                    float wgt = (g == 0 || g == FREQ_ - 1) ? 1.0f : 2.0f;
                    v = (acc[mf][j][reg] + bias) * (wgt / (float)H_);
                }
                Mx[(size_t)bc * 352 + col] = f2bf(v);
            }
        }
}

// ================= K7: irfft via MFMA + denorm ==============================
__global__ __launch_bounds__(256) void k_irfft(const unsigned short* __restrict__ Mx,
                                               const unsigned short* __restrict__ Tir,
                                               const float* __restrict__ full,
                                               const float* __restrict__ muv,
                                               const float* __restrict__ nrm,
                                               float* __restrict__ ytmp) {
    int bc0 = blockIdx.x * 32;
    int tid = threadIdx.x, w = tid >> 6, lane = tid & 63;
    const int NTB[5] = {0, 6, 11, 16, 21};
    int nt0 = NTB[w], ntn = NTB[w + 1] - nt0;
    int r15 = lane & 15, kg = lane >> 4;
    f32x4 acc[2][6];
    #pragma unroll
    for (int mf = 0; mf < 2; ++mf)
        #pragma unroll
        for (int j = 0; j < 6; ++j) acc[mf][j] = (f32x4){0.f, 0.f, 0.f, 0.f};
    for (int kc = 0; kc < 11; ++kc) {
        short8v a[2];
        #pragma unroll
        for (int mf = 0; mf < 2; ++mf)
            a[mf] = *(const short8v*)(Mx + ((size_t)(bc0 + mf * 16 + r15) * 352 + kc * 32 + kg * 8));
        #pragma unroll
        for (int j = 0; j < 6; ++j) {
            if (j >= ntn) continue;
            short8v bfr = *(const short8v*)(Tir + ((size_t)(kc * 21 + nt0 + j) * 512 + lane * 8));
            #pragma unroll
            for (int mf = 0; mf < 2; ++mf)
                acc[mf][j] = __builtin_amdgcn_mfma_f32_16x16x32_bf16(a[mf], bfr, acc[mf][j], 0, 0, 0);
        }
    }
    #pragma unroll
    for (int mf = 0; mf < 2; ++mf)
        #pragma unroll
        for (int j = 0; j < 6; ++j) {
            if (j >= ntn) continue;
            int h = (nt0 + j) * 16 + r15;
            #pragma unroll
            for (int reg = 0; reg < 4; ++reg) {
                int bc = bc0 + mf * 16 + kg * 4 + reg;
                float y = (full[(size_t)bc * LH_ + L_ + h] + acc[mf][j][reg]) * nrm[bc] + muv[bc];
                ytmp[(size_t)bc * H_ + h] = y;
            }
        }
}

// ================= K8: transpose ytmp[b][c][h] -> out[b][h][c] ===============
__global__ __launch_bounds__(256) void k_out_t(const float* __restrict__ ytmp,
                                               float* __restrict__ out) {
    __shared__ float tile[32][33];
    int b = blockIdx.z;
    int h0 = blockIdx.x * 32, c0 = blockIdx.y * 32;
    int tx = threadIdx.x & 31, ty = threadIdx.x >> 5;
    #pragma unroll
    for (int i = 0; i < 4; ++i) {
        int cc = c0 + ty + i * 8, hh = h0 + tx;
        if (cc < C_ && hh < H_)
            tile[ty + i * 8][tx] = ytmp[((size_t)b * C_ + cc) * H_ + hh];
    }
    __syncthreads();
    #pragma unroll
    for (int i = 0; i < 4; ++i) {
        int hh = h0 + ty + i * 8, cc = c0 + tx;
        if (cc < C_ && hh < H_)
            out[((size_t)b * H_ + hh) * C_ + cc] = tile[tx][ty + i * 8];
    }
}

extern "C" void kernel_launch(void* const* d_in, const int* in_sizes, int n_in,
                              void* d_out, int out_size, void* d_ws, size_t ws_size,
                              hipStream_t stream) {
    const float* x     = (const float*)d_in[0];
    const float* r     = (const float*)d_in[1];
    const float* Wb    = (const float*)d_in[2];
    const float* bb    = (const float*)d_in[3];
    const float* Wc    = (const float*)d_in[4];
    const float* bcv   = (const float*)d_in[5];
    const float* st_re = (const float*)d_in[6];
    const float* st_im = (const float*)d_in[7];
    const float* Wm_re = (const float*)d_in[8];
    const float* Wm_im = (const float*)d_in[9];
    const float* bm_re = (const float*)d_in[10];
    const float* bm_im = (const float*)d_in[11];
    const int* leader  = (const int*)d_in[12];
    const int* shiftp  = (const int*)d_in[13];
    float* out = (float*)d_out;

    char* w = (char*)d_ws;
    auto carve = [&](size_t bytes) {
        char* p = w;
        w += (bytes + 255) & ~(size_t)255;
        return (void*)p;
    };
    unsigned short* Tdft = (unsigned short*)carve((size_t)11 * 22 * 512 * 2);
    unsigned short* Tir  = (unsigned short*)carve((size_t)11 * 21 * 512 * 2);
    unsigned short* W2   = (unsigned short*)carve((size_t)32 * 22 * 512 * 2);
    unsigned short* Wbsw = (unsigned short*)carve((size_t)16 * 21 * 512 * 2);
    float2*         stc2 = (float2*)carve((size_t)S_ * G_ * FREQ_ * 8);
    float*          full = (float*)carve((size_t)BCN_ * LH_ * 4);
    unsigned short* xnbf = (unsigned short*)carve((size_t)BCN_ * L_ * 2);
    float*          muv  = (float*)carve((size_t)BCN_ * 4);
    float*          nrm  = (float*)carve((size_t)BCN_ * 4);
    float*          pbuf = (float*)carve((size_t)BCN_ * 8 * 4);
    unsigned short* zbf  = (unsigned short*)carve((size_t)BCN_ * 1024 * 2);
    char*           Xreg = (char*)carve((size_t)BCN_ * 9 * 352 * 2);   // 65.1 MB
    unsigned short* Xbf  = (unsigned short*)Xreg;
    unsigned short* Mx   = (unsigned short*)Xreg;                       // reuse after k_z (X dead)
    float*          ytmp = (float*)(Xreg + (size_t)16 * 1024 * 1024);   // disjoint from Mx (7.3 MB)

    hipLaunchKernelGGL(k_prep_dft, dim3(11 * 22), dim3(64), 0, stream, Tdft);
    hipLaunchKernelGGL(k_prep_ir,  dim3(11 * 21), dim3(64), 0, stream, Tir);
    hipLaunchKernelGGL(k_prep_w2,  dim3(32 * 22), dim3(64), 0, stream, Wm_re, Wm_im, W2);
    hipLaunchKernelGGL(k_prep_wb,  dim3(16 * 21), dim3(64), 0, stream, Wb, Wbsw);
    hipLaunchKernelGGL(k_prep_st,  dim3((S_ * G_ * FREQ_ + 255) / 256), dim3(256), 0, stream,
                       st_re, st_im, stc2);
    hipLaunchKernelGGL(k_ln, dim3(BCN_), dim3(256), 0, stream, x, full, xnbf, muv, nrm);
    hipLaunchKernelGGL(k_yhat, dim3(BCN_ / 32), dim3(256), 0, stream, xnbf, Wbsw, bb, full);
    hipLaunchKernelGGL(k_p, dim3(BCN_), dim3(64), 0, stream, full, r, Wc, bcv, pbuf);
    hipLaunchKernelGGL(k_dft, dim3(BCN_ / 4), dim3(256), 0, stream, full, leader, shiftp, Tdft, Xbf);
    hipLaunchKernelGGL(k_z, dim3(BCN_ / 4), dim3(256), 0, stream, Xbf, pbuf, stc2, zbf);
    hipLaunchKernelGGL(k_mix, dim3(BCN_ / 32), dim3(256), 0, stream, zbf, W2, bm_re, bm_im, Mx);
    hipLaunchKernelGGL(k_irfft, dim3(BCN_ / 32), dim3(256), 0, stream, Mx, Tir, full, muv, nrm, ytmp);
    hipLaunchKernelGGL(k_out_t, dim3((H_ + 31) / 32, (C_ + 31) / 32, B_), dim3(256), 0, stream,
                       ytmp, out);
}

// Round 4
// 475.951 us; speedup vs baseline: 8.0773x; 1.1471x over previous
//
#include <hip/hip_runtime.h>
#include <math.h>

#define B_ 32
#define L_ 512
#define H_ 336
#define C_ 321
#define K_ 8
#define S_ 8
#define FREQ_ 169   // H/2+1
#define G_ 17       // 2K+1
#define LH_ 848     // L+H
#define F_FEAT 520  // L+K
#define EPS_ 1e-5f
#define BCN_ (B_ * C_)   // 10272
#define BCB_ 7           // bc per k_dftz block (63 of 64 M-rows used)

#ifndef M_PIf
#define M_PIf 3.14159265358979323846f
#endif

typedef __attribute__((ext_vector_type(8))) short short8v;
typedef __attribute__((ext_vector_type(4))) float f32x4;

__device__ __forceinline__ unsigned short f2bf(float x) {
    unsigned u = __builtin_bit_cast(unsigned, x);
    u += 0x7FFFu + ((u >> 16) & 1u);
    return (unsigned short)(u >> 16);
}
__device__ __forceinline__ float bf2f(unsigned short h) {
    return __builtin_bit_cast(float, (unsigned)h << 16);
}

// ================= prep kernels: build MFMA-fragment-swizzled B matrices ==========
// Fragment layout (16x16x32 bf16): b-frag lane l holds B[kc*32 + (l>>4)*8 + i][nt*16 + (l&15)].
// Stored flat: elem((kc*NT + nt)*512 + l*8 + i).

// DFT table: K=352 (336 used), N=352 (338 used). col 2f=cos(2pi k f/H), 2f+1=-sin.
__global__ void k_prep_dft(unsigned short* __restrict__ T) {   // grid 11*22, 64 thr
    int blk = blockIdx.x, kc = blk / 22, nt = blk % 22, lane = threadIdx.x;
    int n = nt * 16 + (lane & 15);
    int kb = kc * 32 + (lane >> 4) * 8;
    int f = n >> 1;
    unsigned short* dst = T + (size_t)blk * 512 + lane * 8;
    for (int i = 0; i < 8; ++i) {
        int k = kb + i;
        float val = 0.f;
        if (k < H_ && n < 2 * FREQ_) {
            int m = (k * f) % H_;
            float s, c;
            sincosf((float)m * (2.0f * M_PIf / (float)H_), &s, &c);
            val = (n & 1) ? -s : c;
        }
        dst[i] = f2bf(val);
    }
}

// irfft table: K=352 (338 used; row 2f = cos, 2f+1 = -sin), N=336.
__global__ void k_prep_ir(unsigned short* __restrict__ T) {    // grid 11*21, 64 thr
    int blk = blockIdx.x, kc = blk / 21, nt = blk % 21, lane = threadIdx.x;
    int h = nt * 16 + (lane & 15);
    int kb = kc * 32 + (lane >> 4) * 8;
    unsigned short* dst = T + (size_t)blk * 512 + lane * 8;
    for (int i = 0; i < 8; ++i) {
        int k = kb + i;
        float val = 0.f;
        if (k < 2 * FREQ_) {
            int f = k >> 1;
            int m = (f * h) % H_;
            float s, c;
            sincosf((float)m * (2.0f * M_PIf / (float)H_), &s, &c);
            val = (k & 1) ? -s : c;
        }
        dst[i] = f2bf(val);
    }
}

// Mixing matrix: K=1024 (rows 0..506 = zr, 512..1018 = zi), N=352 (338 used).
__global__ void k_prep_w2(const float* __restrict__ Wm_re, const float* __restrict__ Wm_im,
                          unsigned short* __restrict__ T) {    // grid 32*22, 64 thr
    int blk = blockIdx.x, kc = blk / 22, nt = blk % 22, lane = threadIdx.x;
    int n = nt * 16 + (lane & 15);
    int kb = kc * 32 + (lane >> 4) * 8;
    int g = n >> 1;
    unsigned short* dst = T + (size_t)blk * 512 + lane * 8;
    for (int i = 0; i < 8; ++i) {
        int k = kb + i;
        float val = 0.f;
        if (n < 2 * FREQ_) {
            if (k < 3 * FREQ_) {
                int j = k;
                val = (n & 1) ? Wm_im[(size_t)g * (3 * FREQ_) + j]
                              : Wm_re[(size_t)g * (3 * FREQ_) + j];
            } else if (k >= 512 && k < 512 + 3 * FREQ_) {
                int j = k - 512;
                val = (n & 1) ? Wm_re[(size_t)g * (3 * FREQ_) + j]
                              : -Wm_im[(size_t)g * (3 * FREQ_) + j];
            }
        }
        dst[i] = f2bf(val);
    }
}

// Wb for y_hat GEMM: B[k][n] = Wb[n][k]. K=512, N=336.
__global__ void k_prep_wb(const float* __restrict__ Wb, unsigned short* __restrict__ T) { // grid 16*21, 64 thr
    int blk = blockIdx.x, kc = blk / 21, nt = blk % 21, lane = threadIdx.x;
    int n = nt * 16 + (lane & 15);
    int kb = kc * 32 + (lane >> 4) * 8;
    unsigned short* dst = T + (size_t)blk * 512 + lane * 8;
    for (int i = 0; i < 8; ++i) {
        int k = kb + i;
        dst[i] = f2bf(Wb[(size_t)n * L_ + k]);
    }
}

// states interleave
__global__ __launch_bounds__(256) void k_prep_st(const float* __restrict__ st_re,
                                                 const float* __restrict__ st_im,
                                                 float2* __restrict__ stc2) {
    int idx = blockIdx.x * 256 + threadIdx.x;
    if (idx < S_ * G_ * FREQ_) stc2[idx] = make_float2(st_re[idx], st_im[idx]);
}

// ================= K1: LayerNorm, coalesced + LDS transpose =================
// grid (6, 32): x-tile of 64 channels, y = batch. 256 threads = 4 waves.
__global__ __launch_bounds__(256) void k_ln2(const float* __restrict__ x,
                                             float* __restrict__ full,
                                             unsigned short* __restrict__ xnbf,
                                             float* __restrict__ muv,
                                             float* __restrict__ nrm) {
    __shared__ float tl[64][65];
    __shared__ float red_s[4][64], red_q[4][64];
    __shared__ float sMu[64], sInv[64];
    int tid = threadIdx.x, w = tid >> 6, lane = tid & 63;
    int b = blockIdx.y, c0 = blockIdx.x * 64;
    int c = c0 + lane;
    bool valid = (c < C_);
    const float* xb = x + ((size_t)b * L_) * C_;

    // phase 1: mean/var, coalesced row reads
    float s = 0.f, q = 0.f;
    for (int l = w; l < L_; l += 4) {
        float v = valid ? xb[(size_t)l * C_ + c] : 0.f;
        s += v; q += v * v;
    }
    red_s[w][lane] = s; red_q[w][lane] = q;
    __syncthreads();
    if (w == 0) {
        float S = red_s[0][lane] + red_s[1][lane] + red_s[2][lane] + red_s[3][lane];
        float Q = red_q[0][lane] + red_q[1][lane] + red_q[2][lane] + red_q[3][lane];
        float mu = S / (float)L_;
        float var = Q / (float)L_ - mu * mu;
        float n = sqrtf(var + EPS_);
        sMu[lane] = mu; sInv[lane] = 1.0f / n;
        if (valid) { muv[(size_t)b * C_ + c] = mu; nrm[(size_t)b * C_ + c] = n; }
    }
    __syncthreads();
    float mu = sMu[lane], inv = sInv[lane];

    // phase 2: normalize + transpose-write, 8 tiles of 64 l
    for (int l0 = 0; l0 < L_; l0 += 64) {
        for (int li = w; li < 64; li += 4) {
            float v = valid ? xb[(size_t)(l0 + li) * C_ + c] : 0.f;
            tl[li][lane] = (v - mu) * inv;
        }
        __syncthreads();
        for (int cr = w; cr < 64; cr += 4) {
            int cc = c0 + cr;
            if (cc < C_) {
                size_t bc = (size_t)b * C_ + cc;
                full[bc * LH_ + l0 + lane] = tl[lane][cr];
                if (lane < 32) {
                    unsigned pk = (unsigned)f2bf(tl[2 * lane][cr]) |
                                  ((unsigned)f2bf(tl[2 * lane + 1][cr]) << 16);
                    ((unsigned*)xnbf)[bc * 256 + l0 / 2 + lane] = pk;
                }
            }
        }
        __syncthreads();
    }
}

// ================= K2: y_hat via MFMA: full[:,512:848] = xn @ Wb^T + bb ======
__global__ __launch_bounds__(256) void k_yhat(const unsigned short* __restrict__ xnbf,
                                              const unsigned short* __restrict__ Wbsw,
                                              const float* __restrict__ bb,
                                              float* __restrict__ full) {
    int bc0 = blockIdx.x * 32;
    int tid = threadIdx.x, w = tid >> 6, lane = tid & 63;
    const int NTB[5] = {0, 6, 11, 16, 21};
    int nt0 = NTB[w], ntn = NTB[w + 1] - nt0;
    int r15 = lane & 15, kg = lane >> 4;
    f32x4 acc[2][6];
    #pragma unroll
    for (int mf = 0; mf < 2; ++mf)
        #pragma unroll
        for (int j = 0; j < 6; ++j) acc[mf][j] = (f32x4){0.f, 0.f, 0.f, 0.f};
    for (int kc = 0; kc < 16; ++kc) {
        short8v a[2];
        #pragma unroll
        for (int mf = 0; mf < 2; ++mf)
            a[mf] = *(const short8v*)(xnbf + ((size_t)(bc0 + mf * 16 + r15) * L_ + kc * 32 + kg * 8));
        #pragma unroll
        for (int j = 0; j < 6; ++j) {
            if (j >= ntn) continue;
            short8v bfr = *(const short8v*)(Wbsw + ((size_t)(kc * 21 + nt0 + j) * 512 + lane * 8));
            #pragma unroll
            for (int mf = 0; mf < 2; ++mf)
                acc[mf][j] = __builtin_amdgcn_mfma_f32_16x16x32_bf16(a[mf], bfr, acc[mf][j], 0, 0, 0);
        }
    }
    #pragma unroll
    for (int mf = 0; mf < 2; ++mf)
        #pragma unroll
        for (int j = 0; j < 6; ++j) {
            if (j >= ntn) continue;
            int n_ = (nt0 + j) * 16 + r15;
            #pragma unroll
            for (int reg = 0; reg < 4; ++reg) {
                int bc = bc0 + mf * 16 + kg * 4 + reg;
                full[(size_t)bc * LH_ + L_ + n_] = acc[mf][j][reg] + bb[n_];
            }
        }
}

// ================= K3: r_soft + feat @ Wc^T + softmax -> p ===================
__global__ __launch_bounds__(64) void k_p(const float* __restrict__ full,
                                          const float* __restrict__ r,
                                          const float* __restrict__ Wc,
                                          const float* __restrict__ bcv,
                                          float* __restrict__ p_out) {
    int bc = blockIdx.x;
    int tid = threadIdx.x;
    __shared__ float rsoft[8];
    if (tid == 0) {
        const float* rr = r + (size_t)bc * K_;
        float a[8]; float m = 1.0f;
        #pragma unroll
        for (int k = 0; k < 8; ++k) { a[k] = fabsf(rr[k]); m = fmaxf(m, a[k]); }
        float Z = expf(1.0f - m);
        float e[8];
        #pragma unroll
        for (int k = 0; k < 8; ++k) { e[k] = expf(a[k] - m); Z += e[k]; }
        float inv = 1.0f / Z;
        #pragma unroll
        for (int k = 0; k < 8; ++k) rsoft[k] = e[k] * inv;
    }
    __syncthreads();
    const float* xrow = full + (size_t)bc * LH_;
    float acc[8] = {0.f, 0.f, 0.f, 0.f, 0.f, 0.f, 0.f, 0.f};
    for (int f = tid; f < F_FEAT; f += 64) {
        float xf = (f < L_) ? xrow[f] : rsoft[f - L_];
        #pragma unroll
        for (int s = 0; s < 8; ++s) acc[s] += xf * Wc[s * F_FEAT + f];
    }
    #pragma unroll
    for (int s = 0; s < 8; ++s) {
        #pragma unroll
        for (int off = 32; off > 0; off >>= 1) acc[s] += __shfl_down(acc[s], off);
    }
    if (tid == 0) {
        float m = -1e30f;
        #pragma unroll
        for (int s = 0; s < 8; ++s) { acc[s] += bcv[s]; m = fmaxf(m, acc[s]); }
        float Z = 0.f; float e[8];
        #pragma unroll
        for (int s = 0; s < 8; ++s) { e[s] = expf(acc[s] - m); Z += e[s]; }
        float inv = 1.0f / Z;
        #pragma unroll
        for (int s = 0; s < 8; ++s) p_out[(size_t)bc * 8 + s] = e[s] * inv;
    }
}

// ================= K4: fused DFT (MFMA) + filter-combine -> z ================
// Block: 7 bc x 9 signals = 63 of 64 A-rows. A LDS reused for X after MFMA.
// z layout per bc (1024): [0..168]=z1r,[169..337]=z2r,[338..506]=z3r,[507..511]=0,
//                         [512..680]=z1i,[681..849]=z2i,[850..1018]=z3i,[1019..1023]=0
__global__ __launch_bounds__(256) void k_dftz(const float* __restrict__ full,
                                              const int* __restrict__ leader,
                                              const int* __restrict__ shiftp,
                                              const unsigned short* __restrict__ Tsw,
                                              const float* __restrict__ pbuf,
                                              const float2* __restrict__ stc2,
                                              unsigned short* __restrict__ zbf) {
    __shared__ unsigned short A[64 * 360];
    __shared__ float psL[BCB_][8];
    int tid = threadIdx.x, w = tid >> 6, lane = tid & 63;
    int bc0 = blockIdx.x * BCB_;
    unsigned* A32 = (unsigned*)A;
    for (int i = tid; i < 64 * 180; i += 256) A32[i] = 0;
    if (tid < BCB_ * 8) {
        int bcl = tid >> 3, s = tid & 7;
        int bc = bc0 + bcl;
        psL[bcl][s] = (bc < BCN_) ? pbuf[(size_t)bc * 8 + s] : 0.f;
    }
    __syncthreads();

    // gather 63 rows (row = bcl*9 + k)
    for (int rr = w; rr < 63; rr += 4) {
        int bcl = rr / 9, k = rr - bcl * 9;
        int bc = bc0 + bcl;
        if (bc < BCN_) {
            int b = bc / C_;
            const float* src;
            if (k < 8) {
                int lead = leader[(size_t)bc * K_ + k];
                int sh = shiftp[(size_t)bc * K_ + k];
                src = full + ((size_t)b * C_ + lead) * LH_ + (L_ - sh);
            } else {
                src = full + (size_t)bc * LH_ + L_;
            }
            unsigned* dst = A32 + rr * 180;
            for (int j = lane; j < 168; j += 64) {
                float2 v = *(const float2*)(src + 2 * j);
                dst[j] = (unsigned)f2bf(v.x) | ((unsigned)f2bf(v.y) << 16);
            }
        }
    }
    __syncthreads();

    // MFMA: 4 M-frags x (<=6) N-frags x 11 K-tiles
    const int NTB[5] = {0, 6, 12, 17, 22};
    int nt0 = NTB[w], ntn = NTB[w + 1] - nt0;
    int r15 = lane & 15, kg = lane >> 4;
    f32x4 acc[4][6];
    #pragma unroll
    for (int mf = 0; mf < 4; ++mf)
        #pragma unroll
        for (int j = 0; j < 6; ++j) acc[mf][j] = (f32x4){0.f, 0.f, 0.f, 0.f};
    for (int kc = 0; kc < 11; ++kc) {
        short8v a[4];
        #pragma unroll
        for (int mf = 0; mf < 4; ++mf)
            a[mf] = *(const short8v*)(A + (size_t)(mf * 16 + r15) * 360 + kc * 32 + kg * 8);
        #pragma unroll
        for (int j = 0; j < 6; ++j) {
            if (j >= ntn) continue;
            short8v bfr = *(const short8v*)(Tsw + ((size_t)(kc * 22 + nt0 + j) * 512 + lane * 8));
            #pragma unroll
            for (int mf = 0; mf < 4; ++mf)
                acc[mf][j] = __builtin_amdgcn_mfma_f32_16x16x32_bf16(a[mf], bfr, acc[mf][j], 0, 0, 0);
        }
    }
    __syncthreads();   // A dead; safe to overwrite with X

    // store X (bf16) into LDS: A[row*360 + col], col = 2f | 2f+1
    #pragma unroll
    for (int mf = 0; mf < 4; ++mf)
        #pragma unroll
        for (int j = 0; j < 6; ++j) {
            if (j >= ntn) continue;
            int col = (nt0 + j) * 16 + r15;
            #pragma unroll
            for (int reg = 0; reg < 4; ++reg) {
                int row = mf * 16 + kg * 4 + reg;
                A[row * 360 + col] = f2bf(acc[mf][j][reg]);
            }
        }
    __syncthreads();

    // combine -> z
    for (int idx = tid; idx < BCB_ * FREQ_; idx += 256) {
        int bcl = idx / FREQ_, f = idx - bcl * FREQ_;
        int bc = bc0 + bcl;
        if (bc >= BCN_) continue;
        float Xre[9], Xim[9];
        #pragma unroll
        for (int k = 0; k < 9; ++k) {
            unsigned v = A32[(bcl * 9 + k) * 180 + f];
            Xre[k] = bf2f((unsigned short)(v & 0xffff));
            Xim[k] = bf2f((unsigned short)(v >> 16));
        }
        float ps[8];
        #pragma unroll
        for (int s = 0; s < 8; ++s) ps[s] = psL[bcl][s];
        float Yr = Xre[8], Yi = Xim[8];
        float z1r = 0.f, z1i = 0.f, z2r = 0.f, z2i = 0.f;
        #pragma unroll
        for (int k = 0; k < 8; ++k) {
            float f1r = 0.f, f1i = 0.f, f2r = 0.f, f2i = 0.f;
            #pragma unroll
            for (int s = 0; s < 8; ++s) {
                float2 v1 = stc2[(size_t)s * (G_ * FREQ_) + k * FREQ_ + f];
                float2 v2 = stc2[(size_t)s * (G_ * FREQ_) + (8 + k) * FREQ_ + f];
                f1r += ps[s] * v1.x; f1i += ps[s] * v1.y;
                f2r += ps[s] * v2.x; f2i += ps[s] * v2.y;
            }
            float ar = Xre[k] * f1r - Xim[k] * f1i;
            float ai = Xre[k] * f1i + Xim[k] * f1r;
            z1r += ar; z1i += ai;
            float dr = ar - Yr, di = ai - Yi;
            z2r += dr * f2r - di * f2i;
            z2i += dr * f2i + di * f2r;
        }
        float f3r = 0.f, f3i = 0.f;
        #pragma unroll
        for (int s = 0; s < 8; ++s) {
            float2 v3 = stc2[(size_t)s * (G_ * FREQ_) + 16 * FREQ_ + f];
            f3r += ps[s] * v3.x; f3i += ps[s] * v3.y;
        }
        unsigned short* zrow = zbf + (size_t)bc * 1024;
        zrow[f]       = f2bf(z1r);  zrow[512 + f]       = f2bf(z1i);
        zrow[169 + f] = f2bf(z2r);  zrow[512 + 169 + f] = f2bf(z2i);
        zrow[338 + f] = f2bf(Yr * f3r - Yi * f3i);
        zrow[512 + 338 + f] = f2bf(Yr * f3i + Yi * f3r);
    }
    // zero pads
    if (tid < BCB_ * 10) {
        int bcl = tid / 10, o = tid - bcl * 10;
        int bc = bc0 + bcl;
        if (bc < BCN_) {
            unsigned short* zrow = zbf + (size_t)bc * 1024;
            if (o < 5) zrow[507 + o] = 0;
            else       zrow[1019 + (o - 5)] = 0;
        }
    }
}

// ================= K6: mixing via MFMA ======================================
__global__ __launch_bounds__(256) void k_mix(const unsigned short* __restrict__ zbf,
                                             const unsigned short* __restrict__ W2sw,
                                             const float* __restrict__ bm_re,
                                             const float* __restrict__ bm_im,
                                             unsigned short* __restrict__ Mx) {
    int bc0 = blockIdx.x * 32;
    int tid = threadIdx.x, w = tid >> 6, lane = tid & 63;
    const int NTB[5] = {0, 6, 12, 17, 22};
    int nt0 = NTB[w], ntn = NTB[w + 1] - nt0;
    int r15 = lane & 15, kg = lane >> 4;
    f32x4 acc[2][6];
    #pragma unroll
    for (int mf = 0; mf < 2; ++mf)
        #pragma unroll
        for (int j = 0; j < 6; ++j) acc[mf][j] = (f32x4){0.f, 0.f, 0.f, 0.f};
    for (int kc = 0; kc < 32; ++kc) {
        short8v a[2];
        #pragma unroll
        for (int mf = 0; mf < 2; ++mf)
            a[mf] = *(const short8v*)(zbf + ((size_t)(bc0 + mf * 16 + r15) * 1024 + kc * 32 + kg * 8));
        #pragma unroll
        for (int j = 0; j < 6; ++j) {
            if (j >= ntn) continue;
            short8v bfr = *(const short8v*)(W2sw + ((size_t)(kc * 22 + nt0 + j) * 512 + lane * 8));
            #pragma unroll
            for (int mf = 0; mf < 2; ++mf)
                acc[mf][j] = __builtin_amdgcn_mfma_f32_16x16x32_bf16(a[mf], bfr, acc[mf][j], 0, 0, 0);
        }
    }
    #pragma unroll
    for (int mf = 0; mf < 2; ++mf)
        #pragma unroll
        for (int j = 0; j < 6; ++j) {
            if (j >= ntn) continue;
            int col = (nt0 + j) * 16 + r15;
            #pragma unroll
            for (int reg = 0; reg < 4; ++reg) {
                int bc = bc0 + mf * 16 + kg * 4 + reg;
                float v = 0.f;
                if (col < 2 * FREQ_) {
                    int g = col >> 1;
                    float bias = (col & 1) ? bm_im[g] : bm_re[g];
                    float wgt = (g == 0 || g == FREQ_ - 1) ? 1.0f : 2.0f;
                    v = (acc[mf][j][reg] + bias) * (wgt / (float)H_);
                }
                Mx[(size_t)bc * 352 + col] = f2bf(v);
            }
        }
}

// ================= K7: irfft via MFMA + denorm ==============================
__global__ __launch_bounds__(256) void k_irfft(const unsigned short* __restrict__ Mx,
                                               const unsigned short* __restrict__ Tir,
                                               const float* __restrict__ full,
                                               const float* __restrict__ muv,
                                               const float* __restrict__ nrm,
                                               float* __restrict__ ytmp) {
    int bc0 = blockIdx.x * 32;
    int tid = threadIdx.x, w = tid >> 6, lane = tid & 63;
    const int NTB[5] = {0, 6, 11, 16, 21};
    int nt0 = NTB[w], ntn = NTB[w + 1] - nt0;
    int r15 = lane & 15, kg = lane >> 4;
    f32x4 acc[2][6];
    #pragma unroll
    for (int mf = 0; mf < 2; ++mf)
        #pragma unroll
        for (int j = 0; j < 6; ++j) acc[mf][j] = (f32x4){0.f, 0.f, 0.f, 0.f};
    for (int kc = 0; kc < 11; ++kc) {
        short8v a[2];
        #pragma unroll
        for (int mf = 0; mf < 2; ++mf)
            a[mf] = *(const short8v*)(Mx + ((size_t)(bc0 + mf * 16 + r15) * 352 + kc * 32 + kg * 8));
        #pragma unroll
        for (int j = 0; j < 6; ++j) {
            if (j >= ntn) continue;
            short8v bfr = *(const short8v*)(Tir + ((size_t)(kc * 21 + nt0 + j) * 512 + lane * 8));
            #pragma unroll
            for (int mf = 0; mf < 2; ++mf)
                acc[mf][j] = __builtin_amdgcn_mfma_f32_16x16x32_bf16(a[mf], bfr, acc[mf][j], 0, 0, 0);
        }
    }
    #pragma unroll
    for (int mf = 0; mf < 2; ++mf)
        #pragma unroll
        for (int j = 0; j < 6; ++j) {
            if (j >= ntn) continue;
            int h = (nt0 + j) * 16 + r15;
            #pragma unroll
            for (int reg = 0; reg < 4; ++reg) {
                int bc = bc0 + mf * 16 + kg * 4 + reg;
                float y = (full[(size_t)bc * LH_ + L_ + h] + acc[mf][j][reg]) * nrm[bc] + muv[bc];
                ytmp[(size_t)bc * H_ + h] = y;
            }
        }
}

// ================= K8: transpose ytmp[b][c][h] -> out[b][h][c] ===============
__global__ __launch_bounds__(256) void k_out_t(const float* __restrict__ ytmp,
                                               float* __restrict__ out) {
    __shared__ float tile[32][33];
    int b = blockIdx.z;
    int h0 = blockIdx.x * 32, c0 = blockIdx.y * 32;
    int tx = threadIdx.x & 31, ty = threadIdx.x >> 5;
    #pragma unroll
    for (int i = 0; i < 4; ++i) {
        int cc = c0 + ty + i * 8, hh = h0 + tx;
        if (cc < C_ && hh < H_)
            tile[ty + i * 8][tx] = ytmp[((size_t)b * C_ + cc) * H_ + hh];
    }
    __syncthreads();
    #pragma unroll
    for (int i = 0; i < 4; ++i) {
        int hh = h0 + ty + i * 8, cc = c0 + tx;
        if (cc < C_ && hh < H_)
            out[((size_t)b * H_ + hh) * C_ + cc] = tile[tx][ty + i * 8];
    }
}

extern "C" void kernel_launch(void* const* d_in, const int* in_sizes, int n_in,
                              void* d_out, int out_size, void* d_ws, size_t ws_size,
                              hipStream_t stream) {
    const float* x     = (const float*)d_in[0];
    const float* r     = (const float*)d_in[1];
    const float* Wb    = (const float*)d_in[2];
    const float* bb    = (const float*)d_in[3];
    const float* Wc    = (const float*)d_in[4];
    const float* bcv   = (const float*)d_in[5];
    const float* st_re = (const float*)d_in[6];
    const float* st_im = (const float*)d_in[7];
    const float* Wm_re = (const float*)d_in[8];
    const float* Wm_im = (const float*)d_in[9];
    const float* bm_re = (const float*)d_in[10];
    const float* bm_im = (const float*)d_in[11];
    const int* leader  = (const int*)d_in[12];
    const int* shiftp  = (const int*)d_in[13];
    float* out = (float*)d_out;

    char* w = (char*)d_ws;
    auto carve = [&](size_t bytes) {
        char* p = w;
        w += (bytes + 255) & ~(size_t)255;
        return (void*)p;
    };
    unsigned short* Tdft = (unsigned short*)carve((size_t)11 * 22 * 512 * 2);
    unsigned short* Tir  = (unsigned short*)carve((size_t)11 * 21 * 512 * 2);
    unsigned short* W2   = (unsigned short*)carve((size_t)32 * 22 * 512 * 2);
    unsigned short* Wbsw = (unsigned short*)carve((size_t)16 * 21 * 512 * 2);
    float2*         stc2 = (float2*)carve((size_t)S_ * G_ * FREQ_ * 8);
    float*          full = (float*)carve((size_t)BCN_ * LH_ * 4);
    unsigned short* xnbf = (unsigned short*)carve((size_t)BCN_ * L_ * 2);
    float*          muv  = (float*)carve((size_t)BCN_ * 4);
    float*          nrm  = (float*)carve((size_t)BCN_ * 4);
    float*          pbuf = (float*)carve((size_t)BCN_ * 8 * 4);
    unsigned short* zbf  = (unsigned short*)carve((size_t)BCN_ * 1024 * 2);
    unsigned short* Mx   = (unsigned short*)carve((size_t)BCN_ * 352 * 2);
    float*          ytmp = (float*)carve((size_t)BCN_ * H_ * 4);

    hipLaunchKernelGGL(k_prep_dft, dim3(11 * 22), dim3(64), 0, stream, Tdft);
    hipLaunchKernelGGL(k_prep_ir,  dim3(11 * 21), dim3(64), 0, stream, Tir);
    hipLaunchKernelGGL(k_prep_w2,  dim3(32 * 22), dim3(64), 0, stream, Wm_re, Wm_im, W2);
    hipLaunchKernelGGL(k_prep_wb,  dim3(16 * 21), dim3(64), 0, stream, Wb, Wbsw);
    hipLaunchKernelGGL(k_prep_st,  dim3((S_ * G_ * FREQ_ + 255) / 256), dim3(256), 0, stream,
                       st_re, st_im, stc2);
    hipLaunchKernelGGL(k_ln2, dim3(6, 32), dim3(256), 0, stream, x, full, xnbf, muv, nrm);
    hipLaunchKernelGGL(k_yhat, dim3(BCN_ / 32), dim3(256), 0, stream, xnbf, Wbsw, bb, full);
    hipLaunchKernelGGL(k_p, dim3(BCN_), dim3(64), 0, stream, full, r, Wc, bcv, pbuf);
    hipLaunchKernelGGL(k_dftz, dim3((BCN_ + BCB_ - 1) / BCB_), dim3(256), 0, stream,
                       full, leader, shiftp, Tdft, pbuf, stc2, zbf);
    hipLaunchKernelGGL(k_mix, dim3(BCN_ / 32), dim3(256), 0, stream, zbf, W2, bm_re, bm_im, Mx);
    hipLaunchKernelGGL(k_irfft, dim3(BCN_ / 32), dim3(256), 0, stream, Mx, Tir, full, muv, nrm, ytmp);
    hipLaunchKernelGGL(k_out_t, dim3((H_ + 31) / 32, (C_ + 31) / 32, B_), dim3(256), 0, stream,
                       ytmp, out);
}